// Round 12
// baseline (566.634 us; speedup 1.0000x reference)
//
#include <hip/hip_runtime.h>

// ---------------------------------------------------------------------------
// GCNConv (norm + linear + gather/scatter aggregate) + bias + PReLU
// N=100000 nodes, E=3200000 edges, IN_C=HID=128, all f32 in/out.
//
// R11 = R10 with the nontemporal-store compile fix (native ext_vector float2).
// R10: channel-tiled 8-pass aggregate.
//  - h stored tile-major: ht[8][n][16ch bf16 = 32B]; per pass a tile slab is
//    3.2MB < 4MB per-XCD L2 -> gathers become L2 hits (R9: 380MB random L3
//    traffic at 3.4TB/s was the wall; compulsory floor is 8 XCD x 3.2MB/tile).
//  - grid (nodeblocks, 8): y = tile, x-major dispatch keeps all XCDs in the
//    same tile phase.
//  - per-edge stream = one u32 csr2 = src<<15 | q15(dinv[src]*ew), read
//    nontemporally (zero reuse); out written nontemporally (keep L2 for slab).
//  - wave = 1 node: 8 edge-groups x 8 lanes (16ch/edge), shfl_xor reduce.
// Preprocessing (R8): zero-global-atomic bucket counting sort by col>>6.
// ---------------------------------------------------------------------------

#define NBLK    512          // blocks for p1/p2 (same edge mapping)
#define MAXBKT  1600         // >= ceil(100000/64) = 1563
#define QSCALE  32767.0f
#define NTILE   8            // channel tiles (16 ch = 32B per node per tile)

typedef float vfloat2 __attribute__((ext_vector_type(2)));  // native, NT-storable

__device__ __forceinline__ unsigned bf16pack2(float a, float b) {
    unsigned ua = __float_as_uint(a);
    ua = (ua + 0x7fffu + ((ua >> 16) & 1u)) >> 16;   // RNE
    unsigned ub = __float_as_uint(b);
    ub = (ub + 0x7fffu + ((ub >> 16) & 1u)) >> 16;
    return ua | (ub << 16);
}

__device__ __forceinline__ float2 bf16unpack2(unsigned u) {
    return make_float2(__uint_as_float(u << 16),
                       __uint_as_float(u & 0xffff0000u));
}

// ---- pass 1: per-(bucket,block) counts via LDS ----------------------------
__global__ __launch_bounds__(256) void p1_hist(const int* __restrict__ col,
                                               unsigned* __restrict__ hist,
                                               int e, int nbkt, int epb) {
    __shared__ unsigned lh[MAXBKT];
    int b = blockIdx.x;
    for (int k = threadIdx.x; k < nbkt; k += 256) lh[k] = 0;
    __syncthreads();
    int s = b * epb, en = s + epb; if (en > e) en = e;
    for (int i = s + threadIdx.x; i < en; i += 256)
        atomicAdd(&lh[col[i] >> 6], 1u);           // LDS atomic
    __syncthreads();
    for (int k = threadIdx.x; k < nbkt; k += 256)
        hist[(size_t)k * NBLK + b] = lh[k];
}

// ---- generic 3-phase exclusive scan over m counts -------------------------
__global__ __launch_bounds__(1024) void scan_partial2(
    const unsigned* __restrict__ a, unsigned* __restrict__ part, int m) {
    __shared__ unsigned red[1024];
    int t = threadIdx.x, i = blockIdx.x * 1024 + t;
    red[t] = (i < m) ? a[i] : 0;
    __syncthreads();
    #pragma unroll
    for (int d = 512; d > 0; d >>= 1) {
        if (t < d) red[t] += red[t + d];
        __syncthreads();
    }
    if (t == 0) part[blockIdx.x] = red[0];
}

__global__ __launch_bounds__(1024) void scan_base2(
    unsigned* __restrict__ part, int nb, int* __restrict__ offs, int n, int e) {
    __shared__ unsigned s[1024];
    int t = threadIdx.x;
    unsigned v = (t < nb) ? part[t] : 0;
    s[t] = v;
    __syncthreads();
    for (int d = 1; d < 1024; d <<= 1) {
        unsigned add = (t >= d) ? s[t - d] : 0;
        __syncthreads();
        s[t] += add;
        __syncthreads();
    }
    if (t < nb) part[t] = s[t] - v;   // exclusive base per scan-block
    if (t == 0) offs[n] = e;
}

__global__ __launch_bounds__(1024) void scan_write2(
    unsigned* __restrict__ a, const unsigned* __restrict__ part, int m) {
    __shared__ unsigned s[1024];
    int t = threadIdx.x, i = blockIdx.x * 1024 + t;
    unsigned v = (i < m) ? a[i] : 0;
    s[t] = v;
    __syncthreads();
    for (int d = 1; d < 1024; d <<= 1) {
        unsigned add = (t >= d) ? s[t - d] : 0;
        __syncthreads();
        s[t] += add;
        __syncthreads();
    }
    if (i < m) a[i] = part[blockIdx.x] + s[t] - v;   // exclusive, in place
}

// ---- pass 2: scatter payloads into reserved (bucket,block) ranges ---------
__global__ __launch_bounds__(256) void p2_scatter(
    const int* __restrict__ col, const int* __restrict__ row,
    const float* __restrict__ ew, const unsigned* __restrict__ base,
    unsigned long long* __restrict__ pay, int e, int nbkt, int epb) {
    __shared__ unsigned lbase[MAXBKT];
    __shared__ unsigned lcur[MAXBKT];
    int b = blockIdx.x;
    for (int k = threadIdx.x; k < nbkt; k += 256) {
        lbase[k] = base[(size_t)k * NBLK + b];
        lcur[k] = 0;
    }
    __syncthreads();
    int s = b * epb, en = s + epb; if (en > e) en = e;
    for (int i = s + threadIdx.x; i < en; i += 256) {
        int c = col[i];
        int bk = c >> 6;
        unsigned q  = (unsigned)(ew[i] * QSCALE + 0.5f);     // <= 32767
        unsigned lo = ((unsigned)row[i] << 15) | q;          // src17 | q15
        unsigned rk = atomicAdd(&lcur[bk], 1u);              // LDS atomic
        pay[(size_t)lbase[bk] + rk] =
            ((unsigned long long)(unsigned)(c & 63) << 32) | lo;
    }
}

// ---- pass 3: per-bucket local counting sort -> csr/offs/dinv --------------
__global__ __launch_bounds__(256) void p3_build(
    const unsigned long long* __restrict__ pay,
    const unsigned* __restrict__ histBase,
    unsigned* __restrict__ csr, int* __restrict__ offs,
    float* __restrict__ dinv, int n, int nbkt, int e) {
    __shared__ unsigned cnt[64], wsum[64], lofs[64], cur[64];
    int bk = blockIdx.x;
    int zs = (int)histBase[(size_t)bk * NBLK];
    int ze = (bk + 1 < nbkt) ? (int)histBase[(size_t)(bk + 1) * NBLK] : e;
    int t = threadIdx.x;
    if (t < 64) { cnt[t] = 0; wsum[t] = 0; cur[t] = 0; }
    __syncthreads();
    for (int p = zs + t; p < ze; p += 256) {
        unsigned long long v = pay[p];
        int l = (int)(v >> 32) & 63;
        atomicAdd(&cnt[l], 1u);
        atomicAdd(&wsum[l], (unsigned)v & 0x7fffu);
    }
    __syncthreads();
    if (t == 0) {
        unsigned run = 0;
        for (int l = 0; l < 64; ++l) { lofs[l] = run; run += cnt[l]; }
    }
    __syncthreads();
    for (int p = zs + t; p < ze; p += 256) {         // zone is L2-hot (16KB)
        unsigned long long v = pay[p];
        int l = (int)(v >> 32) & 63;
        unsigned rk = atomicAdd(&cur[l], 1u);
        csr[zs + lofs[l] + rk] = (unsigned)v;        // src<<15 | q15
    }
    if (t < 64) {
        int node = bk * 64 + t;
        if (node < n) {
            offs[node] = zs + (int)lofs[t];
            float dg = 1.0f + (float)wsum[t] * (1.0f / QSCALE);  // self-loop
            dinv[node] = rsqrtf(dg);
        }
    }
}

// ---- csr2_fill: csr2 = src<<15 | q15(dinv[src]*ew) ------------------------
__global__ __launch_bounds__(256) void csr2_fill(const unsigned* __restrict__ csr,
                                                 const float* __restrict__ dinv,
                                                 unsigned* __restrict__ csr2, int e) {
    int i = blockIdx.x * 256 + threadIdx.x;
    if (i < e) {
        unsigned v = csr[i];
        float a = dinv[v >> 15] * ((float)(v & 0x7fffu) * (1.0f / QSCALE));
        csr2[i] = (v & 0xffff8000u) | (unsigned)(a * QSCALE + 0.5f);
    }
}

// ---- ht = bf16(x @ W.T), tile-major: ht[tile][node][16ch] -----------------
__global__ __launch_bounds__(256) void gemm_kernel(const float* __restrict__ x,
                                                   const float* __restrict__ W,
                                                   unsigned* __restrict__ ht, int n) {
    __shared__ float Wt[128][128];  // 64 KB
    int t = threadIdx.x;
    const float4* W4 = (const float4*)W;
    #pragma unroll
    for (int it = 0; it < 16; ++it) {
        int i = t + it * 256;        // float4 slot: o = i>>5 (W row), kq = i&31
        float4 v = W4[i];
        int o  = i >> 5;
        int kb = (i & 31) << 2;
        Wt[kb + 0][o ^ (((kb + 0) & 7) << 2)] = v.x;
        Wt[kb + 1][o ^ (((kb + 1) & 7) << 2)] = v.y;
        Wt[kb + 2][o ^ (((kb + 2) & 7) << 2)] = v.z;
        Wt[kb + 3][o ^ (((kb + 3) & 7) << 2)] = v.w;
    }
    __syncthreads();

    int tc = t & 31;
    int rs = t >> 5;
    int r0 = blockIdx.x * 64 + rs * 8;
    if (r0 >= n) return;            // after the sync: safe
    const float4* x4 = (const float4*)x;

    float acc[8][4];
    #pragma unroll
    for (int ri = 0; ri < 8; ++ri)
        #pragma unroll
        for (int j = 0; j < 4; ++j) acc[ri][j] = 0.0f;

    int rcnt = n - r0; if (rcnt > 8) rcnt = 8;

    // tiled output address (uint2 units): tile slab n*4, node 4, chunk tc&3
    uint2* h2 = (uint2*)ht;
    size_t obase = (size_t)(tc >> 2) * n * 4 + (tc & 3);

    if (rcnt == 8) {
        for (int kq = 0; kq < 32; ++kq) {
            int kb = kq << 2;
            float4 wv0 = *(const float4*)&Wt[kb + 0][(4 * tc) ^ (((kb + 0) & 7) << 2)];
            float4 wv1 = *(const float4*)&Wt[kb + 1][(4 * tc) ^ (((kb + 1) & 7) << 2)];
            float4 wv2 = *(const float4*)&Wt[kb + 2][(4 * tc) ^ (((kb + 2) & 7) << 2)];
            float4 wv3 = *(const float4*)&Wt[kb + 3][(4 * tc) ^ (((kb + 3) & 7) << 2)];
            #pragma unroll
            for (int ri = 0; ri < 8; ++ri) {
                float4 xv = x4[(size_t)(r0 + ri) * 32 + kq];
                acc[ri][0] += xv.x * wv0.x + xv.y * wv1.x + xv.z * wv2.x + xv.w * wv3.x;
                acc[ri][1] += xv.x * wv0.y + xv.y * wv1.y + xv.z * wv2.y + xv.w * wv3.y;
                acc[ri][2] += xv.x * wv0.z + xv.y * wv1.z + xv.z * wv2.z + xv.w * wv3.z;
                acc[ri][3] += xv.x * wv0.w + xv.y * wv1.w + xv.z * wv2.w + xv.w * wv3.w;
            }
        }
        #pragma unroll
        for (int ri = 0; ri < 8; ++ri)
            h2[obase + (size_t)(r0 + ri) * 4] =
                make_uint2(bf16pack2(acc[ri][0], acc[ri][1]),
                           bf16pack2(acc[ri][2], acc[ri][3]));
    } else {
        for (int kq = 0; kq < 32; ++kq) {
            int kb = kq << 2;
            float4 wv0 = *(const float4*)&Wt[kb + 0][(4 * tc) ^ (((kb + 0) & 7) << 2)];
            float4 wv1 = *(const float4*)&Wt[kb + 1][(4 * tc) ^ (((kb + 1) & 7) << 2)];
            float4 wv2 = *(const float4*)&Wt[kb + 2][(4 * tc) ^ (((kb + 2) & 7) << 2)];
            float4 wv3 = *(const float4*)&Wt[kb + 3][(4 * tc) ^ (((kb + 3) & 7) << 2)];
            for (int ri = 0; ri < rcnt; ++ri) {
                float4 xv = x4[(size_t)(r0 + ri) * 32 + kq];
                acc[ri][0] += xv.x * wv0.x + xv.y * wv1.x + xv.z * wv2.x + xv.w * wv3.x;
                acc[ri][1] += xv.x * wv0.y + xv.y * wv1.y + xv.z * wv2.y + xv.w * wv3.y;
                acc[ri][2] += xv.x * wv0.z + xv.y * wv1.z + xv.z * wv2.z + xv.w * wv3.z;
                acc[ri][3] += xv.x * wv0.w + xv.y * wv1.w + xv.z * wv2.w + xv.w * wv3.w;
            }
        }
        for (int ri = 0; ri < rcnt; ++ri)
            h2[obase + (size_t)(r0 + ri) * 4] =
                make_uint2(bf16pack2(acc[ri][0], acc[ri][1]),
                           bf16pack2(acc[ri][2], acc[ri][3]));
    }
}

// ---- aggregate: grid (nodeblk, tile). wave = 1 node; 8 edge-groups x 8
// lanes (16 ch = 32B per edge); shfl_xor folds groups. Slab (3.2MB) is
// L2-resident per XCD; csr2/out streams bypass L2 (nontemporal).
__global__ __launch_bounds__(256) void aggregate_kernel(
    const unsigned* __restrict__ ht, const unsigned* __restrict__ csr2,
    const int* __restrict__ offs, const float* __restrict__ dinv,
    const float* __restrict__ bias, const float* __restrict__ alpha,
    float* __restrict__ out, int n) {
    int tile = blockIdx.y;
    int w = blockIdx.x * 4 + (threadIdx.x >> 6);
    if (w >= n) return;
    int lane = threadIdx.x & 63;
    int g = lane >> 3, c2 = lane & 7;
    const unsigned* slab = ht + (size_t)tile * n * 8;   // u32 units

    int beg = __builtin_amdgcn_readfirstlane(offs[w]);
    int end = __builtin_amdgcn_readfirstlane(offs[w + 1]);

    float ax = 0.0f, ay = 0.0f;
    int i = beg + g;
    for (; i + 8 < end; i += 16) {                      // 2-deep
        unsigned v0 = __builtin_nontemporal_load(&csr2[i]);
        unsigned v1 = __builtin_nontemporal_load(&csr2[i + 8]);
        unsigned u0 = slab[(size_t)(v0 >> 15) * 8 + c2];
        unsigned u1 = slab[(size_t)(v1 >> 15) * 8 + c2];
        float a0 = (float)(v0 & 0x7fffu) * (1.0f / QSCALE);
        float a1 = (float)(v1 & 0x7fffu) * (1.0f / QSCALE);
        float2 h0 = bf16unpack2(u0), h1 = bf16unpack2(u1);
        ax += a0 * h0.x; ay += a0 * h0.y;
        ax += a1 * h1.x; ay += a1 * h1.y;
    }
    if (i < end) {
        unsigned v = __builtin_nontemporal_load(&csr2[i]);
        unsigned u = slab[(size_t)(v >> 15) * 8 + c2];
        float a = (float)(v & 0x7fffu) * (1.0f / QSCALE);
        float2 hv = bf16unpack2(u);
        ax += a * hv.x; ay += a * hv.y;
    }

    // fold the 8 edge-groups (every lane ends with the full sum for its c2)
    ax += __shfl_xor(ax, 8);  ay += __shfl_xor(ay, 8);
    ax += __shfl_xor(ax, 16); ay += __shfl_xor(ay, 16);
    ax += __shfl_xor(ax, 32); ay += __shfl_xor(ay, 32);

    if (lane < 8) {
        float dc = dinv[w];
        float2 hw = bf16unpack2(slab[(size_t)w * 8 + lane]);  // self-loop
        ax += dc * hw.x; ay += dc * hw.y;
        float2 bv = ((const float2*)bias)[tile * 8 + lane];
        float2 av = ((const float2*)alpha)[tile * 8 + lane];
        float ox = ax * dc + bv.x;
        float oy = ay * dc + bv.y;
        ox = ox > 0.0f ? ox : av.x * ox;
        oy = oy > 0.0f ? oy : av.y * oy;
        vfloat2 ov; ov.x = ox; ov.y = oy;                // native vec: NT-storable
        __builtin_nontemporal_store(ov,
            (vfloat2*)&((float2*)out)[(size_t)w * 64 + tile * 8 + lane]);
    }
}

extern "C" void kernel_launch(void* const* d_in, const int* in_sizes, int n_in,
                              void* d_out, int out_size, void* d_ws, size_t ws_size,
                              hipStream_t stream) {
    const float* x     = (const float*)d_in[0];
    const int*   ei    = (const int*)d_in[1];
    const float* ew    = (const float*)d_in[2];
    const float* W     = (const float*)d_in[3];
    const float* bias  = (const float*)d_in[4];
    const float* alpha = (const float*)d_in[5];
    float* out = (float*)d_out;

    const int n = in_sizes[0] / 128;   // 100000
    const int e = in_sizes[1] / 2;     // 3200000
    const int* row = ei;               // edge_index[0] = source (gather)
    const int* col = ei + e;           // edge_index[1] = target (scatter)

    const int nbkt = (n + 63) >> 6;            // 1563 buckets of 64 nodes
    const int m    = nbkt * NBLK;              // 800256 (bucket,block) counts
    const int epb  = (e + NBLK - 1) / NBLK;    // 6250 edges per p1/p2 block
    const int nb2  = (m + 1023) / 1024;        // 782 scan blocks (<=1024)

    // workspace carve-out (256B aligned): ~81 MB total
    char* ws = (char*)d_ws;
    size_t off = 0;
    auto alloc = [&](size_t bytes) -> char* {
        char* p = ws + off;
        off = (off + bytes + 255) & ~(size_t)255;
        return p;
    };
    unsigned*           hist = (unsigned*)          alloc((size_t)m * 4);
    unsigned*           part = (unsigned*)          alloc((size_t)1024 * 4);
    int*                offs = (int*)               alloc((size_t)(n + 1) * 4);
    float*              dinv = (float*)             alloc((size_t)n * 4);
    unsigned long long* pay  = (unsigned long long*)alloc((size_t)e * 8);
    unsigned*           csr  = (unsigned*)          alloc((size_t)e * 4);
    unsigned*           csr2 = (unsigned*)          alloc((size_t)e * 4);
    unsigned*           ht   = (unsigned*)          alloc((size_t)n * 128 * 2);
    (void)ws_size; (void)n_in; (void)out_size;

    p1_hist<<<NBLK, 256, 0, stream>>>(col, hist, e, nbkt, epb);
    scan_partial2<<<nb2, 1024, 0, stream>>>(hist, part, m);
    scan_base2<<<1, 1024, 0, stream>>>(part, nb2, offs, n, e);
    scan_write2<<<nb2, 1024, 0, stream>>>(hist, part, m);
    p2_scatter<<<NBLK, 256, 0, stream>>>(col, row, ew, hist, pay, e, nbkt, epb);
    p3_build<<<nbkt, 256, 0, stream>>>(pay, hist, csr, offs, dinv, n, nbkt, e);
    csr2_fill<<<(e + 255) / 256, 256, 0, stream>>>(csr, dinv, csr2, e);

    int gg = (n + 63) / 64;  // 64 rows per block
    gemm_kernel<<<gg, 256, 0, stream>>>(x, W, ht, n);

    int ga = (n + 3) / 4;    // 4 nodes (waves) per block; y = channel tile
    dim3 grid(ga, NTILE);
    aggregate_kernel<<<grid, 256, 0, stream>>>(ht, csr2, offs, dinv,
                                               bias, alpha, out, n);
}

// Round 13
// 294.407 us; speedup vs baseline: 1.9247x; 1.9247x over previous
//
#include <hip/hip_runtime.h>

// ---------------------------------------------------------------------------
// GCNConv (norm + linear + gather/scatter aggregate) + bias + PReLU
// N=100000 nodes, E=3200000 edges, IN_C=HID=128, all f32 in/out.
//
// R13: single-pass aggregate (R9 shape) + SOURCE-SORTED edge lists.
//  - R12 lesson: 8-pass channel tiling hit the traffic floor (207MB) but 8x'd
//    per-edge instruction overhead -> 391us issue-bound. Revert to one pass.
//  - p3_build counting-sorts each target's list by src>>13 (16 sub-blocks of
//    8192 nodes = 2MB of h each). All waves sweep source space in unison ->
//    active gather window ~L2-sized instead of random over 25.6MB.
//  - csr2 = src<<15 | q15(dinv[src]*ew): one NT-loaded 4B stream per edge.
//  - out stored nontemporally; both NT paths protect L2 for the h window.
// Preprocessing (R8): zero-global-atomic bucket counting sort by col>>6.
// ---------------------------------------------------------------------------

#define NBLK    512          // blocks for p1/p2 (same edge mapping)
#define MAXBKT  1600         // >= ceil(100000/64) = 1563
#define QSCALE  32767.0f
#define SBS     16           // src sub-block slots (src>>13; max 12 for n=100k)

typedef float vfloat2 __attribute__((ext_vector_type(2)));  // NT-storable

__device__ __forceinline__ unsigned bf16pack2(float a, float b) {
    unsigned ua = __float_as_uint(a);
    ua = (ua + 0x7fffu + ((ua >> 16) & 1u)) >> 16;   // RNE
    unsigned ub = __float_as_uint(b);
    ub = (ub + 0x7fffu + ((ub >> 16) & 1u)) >> 16;
    return ua | (ub << 16);
}

__device__ __forceinline__ float2 bf16unpack2(unsigned u) {
    return make_float2(__uint_as_float(u << 16),
                       __uint_as_float(u & 0xffff0000u));
}

// ---- pass 1: per-(bucket,block) counts via LDS ----------------------------
__global__ __launch_bounds__(256) void p1_hist(const int* __restrict__ col,
                                               unsigned* __restrict__ hist,
                                               int e, int nbkt, int epb) {
    __shared__ unsigned lh[MAXBKT];
    int b = blockIdx.x;
    for (int k = threadIdx.x; k < nbkt; k += 256) lh[k] = 0;
    __syncthreads();
    int s = b * epb, en = s + epb; if (en > e) en = e;
    for (int i = s + threadIdx.x; i < en; i += 256)
        atomicAdd(&lh[col[i] >> 6], 1u);           // LDS atomic
    __syncthreads();
    for (int k = threadIdx.x; k < nbkt; k += 256)
        hist[(size_t)k * NBLK + b] = lh[k];
}

// ---- generic 3-phase exclusive scan over m counts -------------------------
__global__ __launch_bounds__(1024) void scan_partial2(
    const unsigned* __restrict__ a, unsigned* __restrict__ part, int m) {
    __shared__ unsigned red[1024];
    int t = threadIdx.x, i = blockIdx.x * 1024 + t;
    red[t] = (i < m) ? a[i] : 0;
    __syncthreads();
    #pragma unroll
    for (int d = 512; d > 0; d >>= 1) {
        if (t < d) red[t] += red[t + d];
        __syncthreads();
    }
    if (t == 0) part[blockIdx.x] = red[0];
}

__global__ __launch_bounds__(1024) void scan_base2(
    unsigned* __restrict__ part, int nb, int* __restrict__ offs, int n, int e) {
    __shared__ unsigned s[1024];
    int t = threadIdx.x;
    unsigned v = (t < nb) ? part[t] : 0;
    s[t] = v;
    __syncthreads();
    for (int d = 1; d < 1024; d <<= 1) {
        unsigned add = (t >= d) ? s[t - d] : 0;
        __syncthreads();
        s[t] += add;
        __syncthreads();
    }
    if (t < nb) part[t] = s[t] - v;   // exclusive base per scan-block
    if (t == 0) offs[n] = e;
}

__global__ __launch_bounds__(1024) void scan_write2(
    unsigned* __restrict__ a, const unsigned* __restrict__ part, int m) {
    __shared__ unsigned s[1024];
    int t = threadIdx.x, i = blockIdx.x * 1024 + t;
    unsigned v = (i < m) ? a[i] : 0;
    s[t] = v;
    __syncthreads();
    for (int d = 1; d < 1024; d <<= 1) {
        unsigned add = (t >= d) ? s[t - d] : 0;
        __syncthreads();
        s[t] += add;
        __syncthreads();
    }
    if (i < m) a[i] = part[blockIdx.x] + s[t] - v;   // exclusive, in place
}

// ---- pass 2: scatter payloads into reserved (bucket,block) ranges ---------
__global__ __launch_bounds__(256) void p2_scatter(
    const int* __restrict__ col, const int* __restrict__ row,
    const float* __restrict__ ew, const unsigned* __restrict__ base,
    unsigned long long* __restrict__ pay, int e, int nbkt, int epb) {
    __shared__ unsigned lbase[MAXBKT];
    __shared__ unsigned lcur[MAXBKT];
    int b = blockIdx.x;
    for (int k = threadIdx.x; k < nbkt; k += 256) {
        lbase[k] = base[(size_t)k * NBLK + b];
        lcur[k] = 0;
    }
    __syncthreads();
    int s = b * epb, en = s + epb; if (en > e) en = e;
    for (int i = s + threadIdx.x; i < en; i += 256) {
        int c = col[i];
        int bk = c >> 6;
        unsigned q  = (unsigned)(ew[i] * QSCALE + 0.5f);     // <= 32767
        unsigned lo = ((unsigned)row[i] << 15) | q;          // src17 | q15
        unsigned rk = atomicAdd(&lcur[bk], 1u);              // LDS atomic
        pay[(size_t)lbase[bk] + rk] =
            ((unsigned long long)(unsigned)(c & 63) << 32) | lo;
    }
}

// ---- pass 3: per-bucket counting sort by (target, src-block) --------------
// Each target's final list is grouped by src>>13 -> aggregate's gathers sweep
// h in ascending-source order (L2-sized moving window across all waves).
__global__ __launch_bounds__(256) void p3_build(
    const unsigned long long* __restrict__ pay,
    const unsigned* __restrict__ histBase,
    unsigned* __restrict__ csr, int* __restrict__ offs,
    float* __restrict__ dinv, int n, int nbkt, int e) {
    __shared__ unsigned cnt[64][SBS], lofs[64][SBS], cur[64][SBS];
    __shared__ unsigned wsum[64], tbase[64], ttot[64];
    int bk = blockIdx.x;
    int zs = (int)histBase[(size_t)bk * NBLK];
    int ze = (bk + 1 < nbkt) ? (int)histBase[(size_t)(bk + 1) * NBLK] : e;
    int t = threadIdx.x;
    for (int k = t; k < 64 * SBS; k += 256) {
        (&cnt[0][0])[k] = 0;
        (&cur[0][0])[k] = 0;
    }
    if (t < 64) wsum[t] = 0;
    __syncthreads();
    for (int p = zs + t; p < ze; p += 256) {
        unsigned long long v = pay[p];
        int l = (int)(v >> 32) & 63;
        unsigned lo = (unsigned)v;
        int sb = (int)((lo >> 15) >> 13);          // src block
        atomicAdd(&cnt[l][sb], 1u);
        atomicAdd(&wsum[l], lo & 0x7fffu);
    }
    __syncthreads();
    if (t < 64) {
        unsigned s = 0;
        #pragma unroll
        for (int j = 0; j < SBS; ++j) s += cnt[t][j];
        ttot[t] = s;
    }
    __syncthreads();
    if (t == 0) {
        unsigned run = 0;
        for (int l = 0; l < 64; ++l) { tbase[l] = run; run += ttot[l]; }
    }
    __syncthreads();
    if (t < 64) {
        unsigned run = tbase[t];
        #pragma unroll
        for (int j = 0; j < SBS; ++j) { lofs[t][j] = run; run += cnt[t][j]; }
    }
    __syncthreads();
    for (int p = zs + t; p < ze; p += 256) {       // zone is L2-hot (16KB)
        unsigned long long v = pay[p];
        int l = (int)(v >> 32) & 63;
        unsigned lo = (unsigned)v;
        int sb = (int)((lo >> 15) >> 13);
        unsigned rk = atomicAdd(&cur[l][sb], 1u);
        csr[zs + lofs[l][sb] + rk] = lo;           // src<<15 | q15(ew)
    }
    if (t < 64) {
        int node = bk * 64 + t;
        if (node < n) {
            offs[node] = zs + (int)tbase[t];
            float dg = 1.0f + (float)wsum[t] * (1.0f / QSCALE);  // self-loop
            dinv[node] = rsqrtf(dg);
        }
    }
}

// ---- csr2_fill: csr2 = src<<15 | q15(dinv[src]*ew)  (order-preserving) ----
__global__ __launch_bounds__(256) void csr2_fill(const unsigned* __restrict__ csr,
                                                 const float* __restrict__ dinv,
                                                 unsigned* __restrict__ csr2, int e) {
    int i = blockIdx.x * 256 + threadIdx.x;
    if (i < e) {
        unsigned v = csr[i];
        float a = dinv[v >> 15] * ((float)(v & 0x7fffu) * (1.0f / QSCALE));
        csr2[i] = (v & 0xffff8000u) | (unsigned)(a * QSCALE + 0.5f);
    }
}

// ---- h = bf16(x @ W.T), row-major h[node][128] ----------------------------
__global__ __launch_bounds__(256) void gemm_kernel(const float* __restrict__ x,
                                                   const float* __restrict__ W,
                                                   unsigned* __restrict__ h, int n) {
    __shared__ float Wt[128][128];  // 64 KB
    int t = threadIdx.x;
    const float4* W4 = (const float4*)W;
    #pragma unroll
    for (int it = 0; it < 16; ++it) {
        int i = t + it * 256;        // float4 slot: o = i>>5 (W row), kq = i&31
        float4 v = W4[i];
        int o  = i >> 5;
        int kb = (i & 31) << 2;
        Wt[kb + 0][o ^ (((kb + 0) & 7) << 2)] = v.x;
        Wt[kb + 1][o ^ (((kb + 1) & 7) << 2)] = v.y;
        Wt[kb + 2][o ^ (((kb + 2) & 7) << 2)] = v.z;
        Wt[kb + 3][o ^ (((kb + 3) & 7) << 2)] = v.w;
    }
    __syncthreads();

    int tc = t & 31;
    int rs = t >> 5;
    int r0 = blockIdx.x * 64 + rs * 8;
    if (r0 >= n) return;            // after the sync: safe
    const float4* x4 = (const float4*)x;

    float acc[8][4];
    #pragma unroll
    for (int ri = 0; ri < 8; ++ri)
        #pragma unroll
        for (int j = 0; j < 4; ++j) acc[ri][j] = 0.0f;

    int rcnt = n - r0; if (rcnt > 8) rcnt = 8;

    if (rcnt == 8) {
        for (int kq = 0; kq < 32; ++kq) {
            int kb = kq << 2;
            float4 wv0 = *(const float4*)&Wt[kb + 0][(4 * tc) ^ (((kb + 0) & 7) << 2)];
            float4 wv1 = *(const float4*)&Wt[kb + 1][(4 * tc) ^ (((kb + 1) & 7) << 2)];
            float4 wv2 = *(const float4*)&Wt[kb + 2][(4 * tc) ^ (((kb + 2) & 7) << 2)];
            float4 wv3 = *(const float4*)&Wt[kb + 3][(4 * tc) ^ (((kb + 3) & 7) << 2)];
            #pragma unroll
            for (int ri = 0; ri < 8; ++ri) {
                float4 xv = x4[(size_t)(r0 + ri) * 32 + kq];
                acc[ri][0] += xv.x * wv0.x + xv.y * wv1.x + xv.z * wv2.x + xv.w * wv3.x;
                acc[ri][1] += xv.x * wv0.y + xv.y * wv1.y + xv.z * wv2.y + xv.w * wv3.y;
                acc[ri][2] += xv.x * wv0.z + xv.y * wv1.z + xv.z * wv2.z + xv.w * wv3.z;
                acc[ri][3] += xv.x * wv0.w + xv.y * wv1.w + xv.z * wv2.w + xv.w * wv3.w;
            }
        }
        uint2* h2 = (uint2*)h;
        #pragma unroll
        for (int ri = 0; ri < 8; ++ri)
            h2[(size_t)(r0 + ri) * 32 + tc] =
                make_uint2(bf16pack2(acc[ri][0], acc[ri][1]),
                           bf16pack2(acc[ri][2], acc[ri][3]));
    } else {
        for (int kq = 0; kq < 32; ++kq) {
            int kb = kq << 2;
            float4 wv0 = *(const float4*)&Wt[kb + 0][(4 * tc) ^ (((kb + 0) & 7) << 2)];
            float4 wv1 = *(const float4*)&Wt[kb + 1][(4 * tc) ^ (((kb + 1) & 7) << 2)];
            float4 wv2 = *(const float4*)&Wt[kb + 2][(4 * tc) ^ (((kb + 2) & 7) << 2)];
            float4 wv3 = *(const float4*)&Wt[kb + 3][(4 * tc) ^ (((kb + 3) & 7) << 2)];
            for (int ri = 0; ri < rcnt; ++ri) {
                float4 xv = x4[(size_t)(r0 + ri) * 32 + kq];
                acc[ri][0] += xv.x * wv0.x + xv.y * wv1.x + xv.z * wv2.x + xv.w * wv3.x;
                acc[ri][1] += xv.x * wv0.y + xv.y * wv1.y + xv.z * wv2.y + xv.w * wv3.y;
                acc[ri][2] += xv.x * wv0.z + xv.y * wv1.z + xv.z * wv2.z + xv.w * wv3.z;
                acc[ri][3] += xv.x * wv0.w + xv.y * wv1.w + xv.z * wv2.w + xv.w * wv3.w;
            }
        }
        uint2* h2 = (uint2*)h;
        for (int ri = 0; ri < rcnt; ++ri)
            h2[(size_t)(r0 + ri) * 32 + tc] =
                make_uint2(bf16pack2(acc[ri][0], acc[ri][1]),
                           bf16pack2(acc[ri][2], acc[ri][3]));
    }
}

// ---- aggregate: one wave per node, lane owns 2 channels (bf16x2 u32) ------
// Single pass; edge lists are src-sorted (p3) so gathers sweep h coherently.
// csr2 NT-loaded; out NT-stored. XCD-chunked swizzle.
__global__ __launch_bounds__(256) void aggregate_kernel(
    const unsigned* __restrict__ h, const unsigned* __restrict__ csr2,
    const int* __restrict__ offs, const float* __restrict__ dinv,
    const float* __restrict__ bias, const float* __restrict__ alpha,
    float* __restrict__ out, int n, int swzq) {
    int bid = blockIdx.x;
    int sb  = swzq ? ((bid & 7) * swzq + (bid >> 3)) : bid;   // bijective: grid%8==0
    int w = sb * 4 + (threadIdx.x >> 6);
    if (w >= n) return;
    int lane = threadIdx.x & 63;

    int beg = __builtin_amdgcn_readfirstlane(offs[w]);
    int end = __builtin_amdgcn_readfirstlane(offs[w + 1]);
    float ax = 0.0f, ay = 0.0f;

    int i = beg;
    int end4 = beg + ((end - beg) & ~3);
    for (; i < end4; i += 4) {
        unsigned v0 = __builtin_nontemporal_load(&csr2[i]);
        unsigned v1 = __builtin_nontemporal_load(&csr2[i + 1]);
        unsigned v2 = __builtin_nontemporal_load(&csr2[i + 2]);
        unsigned v3 = __builtin_nontemporal_load(&csr2[i + 3]);
        unsigned u0 = h[(size_t)(v0 >> 15) * 64 + lane];
        unsigned u1 = h[(size_t)(v1 >> 15) * 64 + lane];
        unsigned u2 = h[(size_t)(v2 >> 15) * 64 + lane];
        unsigned u3 = h[(size_t)(v3 >> 15) * 64 + lane];
        float a0 = (float)(v0 & 0x7fffu) * (1.0f / QSCALE);
        float a1 = (float)(v1 & 0x7fffu) * (1.0f / QSCALE);
        float a2 = (float)(v2 & 0x7fffu) * (1.0f / QSCALE);
        float a3 = (float)(v3 & 0x7fffu) * (1.0f / QSCALE);
        float2 h0 = bf16unpack2(u0), h1 = bf16unpack2(u1);
        float2 h2 = bf16unpack2(u2), h3 = bf16unpack2(u3);
        ax += a0 * h0.x; ay += a0 * h0.y;
        ax += a1 * h1.x; ay += a1 * h1.y;
        ax += a2 * h2.x; ay += a2 * h2.y;
        ax += a3 * h3.x; ay += a3 * h3.y;
    }
    for (; i < end; ++i) {
        unsigned v = __builtin_nontemporal_load(&csr2[i]);
        unsigned u = h[(size_t)(v >> 15) * 64 + lane];
        float a = (float)(v & 0x7fffu) * (1.0f / QSCALE);
        float2 hv = bf16unpack2(u);
        ax += a * hv.x; ay += a * hv.y;
    }

    float dc = dinv[w];
    float2 hc = bf16unpack2(h[(size_t)w * 64 + lane]);  // self: dinv^2 * h[c]
    ax += dc * hc.x; ay += dc * hc.y;

    float2 bv = ((const float2*)bias)[lane];
    float2 av = ((const float2*)alpha)[lane];
    float ox = ax * dc + bv.x;
    float oy = ay * dc + bv.y;
    ox = ox > 0.0f ? ox : av.x * ox;
    oy = oy > 0.0f ? oy : av.y * oy;
    vfloat2 ov; ov.x = ox; ov.y = oy;
    __builtin_nontemporal_store(ov,
        (vfloat2*)&((float2*)out)[(size_t)w * 64 + lane]);
}

extern "C" void kernel_launch(void* const* d_in, const int* in_sizes, int n_in,
                              void* d_out, int out_size, void* d_ws, size_t ws_size,
                              hipStream_t stream) {
    const float* x     = (const float*)d_in[0];
    const int*   ei    = (const int*)d_in[1];
    const float* ew    = (const float*)d_in[2];
    const float* W     = (const float*)d_in[3];
    const float* bias  = (const float*)d_in[4];
    const float* alpha = (const float*)d_in[5];
    float* out = (float*)d_out;

    const int n = in_sizes[0] / 128;   // 100000
    const int e = in_sizes[1] / 2;     // 3200000
    const int* row = ei;               // edge_index[0] = source (gather)
    const int* col = ei + e;           // edge_index[1] = target (scatter)

    const int nbkt = (n + 63) >> 6;            // 1563 buckets of 64 nodes
    const int m    = nbkt * NBLK;              // 800256 (bucket,block) counts
    const int epb  = (e + NBLK - 1) / NBLK;    // 6250 edges per p1/p2 block
    const int nb2  = (m + 1023) / 1024;        // 782 scan blocks (<=1024)

    // workspace carve-out (256B aligned): ~81 MB total
    char* ws = (char*)d_ws;
    size_t off = 0;
    auto alloc = [&](size_t bytes) -> char* {
        char* p = ws + off;
        off = (off + bytes + 255) & ~(size_t)255;
        return p;
    };
    unsigned*           hist = (unsigned*)          alloc((size_t)m * 4);
    unsigned*           part = (unsigned*)          alloc((size_t)1024 * 4);
    int*                offs = (int*)               alloc((size_t)(n + 1) * 4);
    float*              dinv = (float*)             alloc((size_t)n * 4);
    unsigned long long* pay  = (unsigned long long*)alloc((size_t)e * 8);
    unsigned*           csr  = (unsigned*)          alloc((size_t)e * 4);
    unsigned*           csr2 = (unsigned*)          alloc((size_t)e * 4);
    unsigned*           h    = (unsigned*)          alloc((size_t)n * 128 * 2);
    (void)ws_size; (void)n_in; (void)out_size;

    p1_hist<<<NBLK, 256, 0, stream>>>(col, hist, e, nbkt, epb);
    scan_partial2<<<nb2, 1024, 0, stream>>>(hist, part, m);
    scan_base2<<<1, 1024, 0, stream>>>(part, nb2, offs, n, e);
    scan_write2<<<nb2, 1024, 0, stream>>>(hist, part, m);
    p2_scatter<<<NBLK, 256, 0, stream>>>(col, row, ew, hist, pay, e, nbkt, epb);
    p3_build<<<nbkt, 256, 0, stream>>>(pay, hist, csr, offs, dinv, n, nbkt, e);
    csr2_fill<<<(e + 255) / 256, 256, 0, stream>>>(csr, dinv, csr2, e);

    int gg = (n + 63) / 64;  // 64 rows per block
    gemm_kernel<<<gg, 256, 0, stream>>>(x, W, h, n);

    int ga = (n + 3) / 4;    // 4 nodes (waves) per 256-thread block
    int swzq = (ga % 8 == 0) ? ga / 8 : 0;
    aggregate_kernel<<<ga, 256, 0, stream>>>(h, csr2, offs, dinv,
                                             bias, alpha, out, n, swzq);
}

// Round 14
// 288.119 us; speedup vs baseline: 1.9667x; 1.0218x over previous
//
#include <hip/hip_runtime.h>

// ---------------------------------------------------------------------------
// GCNConv (norm + linear + gather/scatter aggregate) + bias + PReLU
// N=100000 nodes, E=3200000 edges, IN_C=HID=128, all f32 in/out.
//
// R14: shrink + overlap preprocessing (aggregate kept at R13 near-floor form).
//  - pay is u32: label(6) | src(17) | q9(ew)  (was u64) -> halves p2 scatter
//    writes and p3 reads. q9 deg/coef error ~0.1% rel, << bf16-h error.
//  - fused_p2_gemm: one dispatch; blocks [0,NBLK) run p2_scatter role,
//    [NBLK, NBLK+gg) run gemm role. Independent work, complementary pipes
//    (p2 mem/LDS-bound, gemm VALU-bound), same 2 blocks/CU LDS budget.
//  - csr = src<<9 | q9; csr2 = src<<15 | q15(dinv[src]*ew) (aggregate as R13:
//    single pass, src-sorted lists, NT edge/out streams, XCD swizzle).
// Preprocessing (R8): zero-global-atomic bucket counting sort by col>>6.
// ---------------------------------------------------------------------------

#define NBLK    512          // p2-role blocks (edge mapping)
#define MAXBKT  1600         // >= ceil(100000/64) = 1563
#define QSCALE  32767.0f
#define Q9      511.0f
#define SBS     16           // src sub-block slots (src>>13; max 12 for n=100k)

typedef float vfloat2 __attribute__((ext_vector_type(2)));  // NT-storable

__device__ __forceinline__ unsigned bf16pack2(float a, float b) {
    unsigned ua = __float_as_uint(a);
    ua = (ua + 0x7fffu + ((ua >> 16) & 1u)) >> 16;   // RNE
    unsigned ub = __float_as_uint(b);
    ub = (ub + 0x7fffu + ((ub >> 16) & 1u)) >> 16;
    return ua | (ub << 16);
}

__device__ __forceinline__ float2 bf16unpack2(unsigned u) {
    return make_float2(__uint_as_float(u << 16),
                       __uint_as_float(u & 0xffff0000u));
}

// ---- pass 1: per-(bucket,block) counts via LDS ----------------------------
__global__ __launch_bounds__(256) void p1_hist(const int* __restrict__ col,
                                               unsigned* __restrict__ hist,
                                               int e, int nbkt, int epb) {
    __shared__ unsigned lh[MAXBKT];
    int b = blockIdx.x;
    for (int k = threadIdx.x; k < nbkt; k += 256) lh[k] = 0;
    __syncthreads();
    int s = b * epb, en = s + epb; if (en > e) en = e;
    for (int i = s + threadIdx.x; i < en; i += 256)
        atomicAdd(&lh[col[i] >> 6], 1u);           // LDS atomic
    __syncthreads();
    for (int k = threadIdx.x; k < nbkt; k += 256)
        hist[(size_t)k * NBLK + b] = lh[k];
}

// ---- generic 3-phase exclusive scan over m counts -------------------------
__global__ __launch_bounds__(1024) void scan_partial2(
    const unsigned* __restrict__ a, unsigned* __restrict__ part, int m) {
    __shared__ unsigned red[1024];
    int t = threadIdx.x, i = blockIdx.x * 1024 + t;
    red[t] = (i < m) ? a[i] : 0;
    __syncthreads();
    #pragma unroll
    for (int d = 512; d > 0; d >>= 1) {
        if (t < d) red[t] += red[t + d];
        __syncthreads();
    }
    if (t == 0) part[blockIdx.x] = red[0];
}

__global__ __launch_bounds__(1024) void scan_base2(
    unsigned* __restrict__ part, int nb, int* __restrict__ offs, int n, int e) {
    __shared__ unsigned s[1024];
    int t = threadIdx.x;
    unsigned v = (t < nb) ? part[t] : 0;
    s[t] = v;
    __syncthreads();
    for (int d = 1; d < 1024; d <<= 1) {
        unsigned add = (t >= d) ? s[t - d] : 0;
        __syncthreads();
        s[t] += add;
        __syncthreads();
    }
    if (t < nb) part[t] = s[t] - v;   // exclusive base per scan-block
    if (t == 0) offs[n] = e;
}

__global__ __launch_bounds__(1024) void scan_write2(
    unsigned* __restrict__ a, const unsigned* __restrict__ part, int m) {
    __shared__ unsigned s[1024];
    int t = threadIdx.x, i = blockIdx.x * 1024 + t;
    unsigned v = (i < m) ? a[i] : 0;
    s[t] = v;
    __syncthreads();
    for (int d = 1; d < 1024; d <<= 1) {
        unsigned add = (t >= d) ? s[t - d] : 0;
        __syncthreads();
        s[t] += add;
        __syncthreads();
    }
    if (i < m) a[i] = part[blockIdx.x] + s[t] - v;   // exclusive, in place
}

// ---- fused: blocks [0,NBLK) = p2_scatter role; rest = gemm role -----------
// p2: scatter u32 payloads (label|src|q9) into reserved (bucket,block) ranges.
// gemm: h = bf16(x @ W.T), row-major h[node][128] (W^T in LDS, XOR-swizzled).
__global__ __launch_bounds__(256) void fused_p2_gemm(
    const int* __restrict__ col, const int* __restrict__ row,
    const float* __restrict__ ew, const unsigned* __restrict__ base,
    unsigned* __restrict__ pay, int e, int nbkt, int epb,
    const float* __restrict__ x, const float* __restrict__ W,
    unsigned* __restrict__ h, int n) {
    __shared__ float smem[128 * 128];   // 64 KB, aliased by both roles
    int bid = blockIdx.x;
    int t = threadIdx.x;

    if (bid < NBLK) {
        // ---------------- p2_scatter role ----------------
        unsigned* lbase = (unsigned*)smem;
        unsigned* lcur  = (unsigned*)smem + MAXBKT;
        int b = bid;
        for (int k = t; k < nbkt; k += 256) {
            lbase[k] = base[(size_t)k * NBLK + b];
            lcur[k] = 0;
        }
        __syncthreads();
        int s = b * epb, en = s + epb; if (en > e) en = e;
        for (int i = s + t; i < en; i += 256) {
            int c = col[i];
            int bk = c >> 6;
            unsigned q = (unsigned)(ew[i] * Q9 + 0.5f);          // <= 511
            unsigned rk = atomicAdd(&lcur[bk], 1u);              // LDS atomic
            pay[(size_t)lbase[bk] + rk] =
                ((unsigned)(c & 63) << 26) | ((unsigned)row[i] << 9) | q;
        }
        return;
    }

    // ---------------- gemm role ----------------
    float (*Wt)[128] = (float (*)[128])smem;
    const float4* W4 = (const float4*)W;
    #pragma unroll
    for (int it = 0; it < 16; ++it) {
        int i = t + it * 256;        // float4 slot: o = i>>5 (W row), kq = i&31
        float4 v = W4[i];
        int o  = i >> 5;
        int kb = (i & 31) << 2;
        Wt[kb + 0][o ^ (((kb + 0) & 7) << 2)] = v.x;
        Wt[kb + 1][o ^ (((kb + 1) & 7) << 2)] = v.y;
        Wt[kb + 2][o ^ (((kb + 2) & 7) << 2)] = v.z;
        Wt[kb + 3][o ^ (((kb + 3) & 7) << 2)] = v.w;
    }
    __syncthreads();

    int tc = t & 31;
    int rs = t >> 5;
    int r0 = (bid - NBLK) * 64 + rs * 8;
    if (r0 >= n) return;            // after the sync: safe
    const float4* x4 = (const float4*)x;

    float acc[8][4];
    #pragma unroll
    for (int ri = 0; ri < 8; ++ri)
        #pragma unroll
        for (int j = 0; j < 4; ++j) acc[ri][j] = 0.0f;

    int rcnt = n - r0; if (rcnt > 8) rcnt = 8;

    if (rcnt == 8) {
        for (int kq = 0; kq < 32; ++kq) {
            int kb = kq << 2;
            float4 wv0 = *(const float4*)&Wt[kb + 0][(4 * tc) ^ (((kb + 0) & 7) << 2)];
            float4 wv1 = *(const float4*)&Wt[kb + 1][(4 * tc) ^ (((kb + 1) & 7) << 2)];
            float4 wv2 = *(const float4*)&Wt[kb + 2][(4 * tc) ^ (((kb + 2) & 7) << 2)];
            float4 wv3 = *(const float4*)&Wt[kb + 3][(4 * tc) ^ (((kb + 3) & 7) << 2)];
            #pragma unroll
            for (int ri = 0; ri < 8; ++ri) {
                float4 xv = x4[(size_t)(r0 + ri) * 32 + kq];
                acc[ri][0] += xv.x * wv0.x + xv.y * wv1.x + xv.z * wv2.x + xv.w * wv3.x;
                acc[ri][1] += xv.x * wv0.y + xv.y * wv1.y + xv.z * wv2.y + xv.w * wv3.y;
                acc[ri][2] += xv.x * wv0.z + xv.y * wv1.z + xv.z * wv2.z + xv.w * wv3.z;
                acc[ri][3] += xv.x * wv0.w + xv.y * wv1.w + xv.z * wv2.w + xv.w * wv3.w;
            }
        }
        uint2* h2 = (uint2*)h;
        #pragma unroll
        for (int ri = 0; ri < 8; ++ri)
            h2[(size_t)(r0 + ri) * 32 + tc] =
                make_uint2(bf16pack2(acc[ri][0], acc[ri][1]),
                           bf16pack2(acc[ri][2], acc[ri][3]));
    } else {
        for (int kq = 0; kq < 32; ++kq) {
            int kb = kq << 2;
            float4 wv0 = *(const float4*)&Wt[kb + 0][(4 * tc) ^ (((kb + 0) & 7) << 2)];
            float4 wv1 = *(const float4*)&Wt[kb + 1][(4 * tc) ^ (((kb + 1) & 7) << 2)];
            float4 wv2 = *(const float4*)&Wt[kb + 2][(4 * tc) ^ (((kb + 2) & 7) << 2)];
            float4 wv3 = *(const float4*)&Wt[kb + 3][(4 * tc) ^ (((kb + 3) & 7) << 2)];
            for (int ri = 0; ri < rcnt; ++ri) {
                float4 xv = x4[(size_t)(r0 + ri) * 32 + kq];
                acc[ri][0] += xv.x * wv0.x + xv.y * wv1.x + xv.z * wv2.x + xv.w * wv3.x;
                acc[ri][1] += xv.x * wv0.y + xv.y * wv1.y + xv.z * wv2.y + xv.w * wv3.y;
                acc[ri][2] += xv.x * wv0.z + xv.y * wv1.z + xv.z * wv2.z + xv.w * wv3.z;
                acc[ri][3] += xv.x * wv0.w + xv.y * wv1.w + xv.z * wv2.w + xv.w * wv3.w;
            }
        }
        uint2* h2 = (uint2*)h;
        for (int ri = 0; ri < rcnt; ++ri)
            h2[(size_t)(r0 + ri) * 32 + tc] =
                make_uint2(bf16pack2(acc[ri][0], acc[ri][1]),
                           bf16pack2(acc[ri][2], acc[ri][3]));
    }
}

// ---- pass 3: per-bucket counting sort by (target, src-block) --------------
// Each target's final list is grouped by src>>13 -> aggregate's gathers sweep
// h in ascending-source order. pay u32: label(6)|src(17)|q9.
__global__ __launch_bounds__(256) void p3_build(
    const unsigned* __restrict__ pay,
    const unsigned* __restrict__ histBase,
    unsigned* __restrict__ csr, int* __restrict__ offs,
    float* __restrict__ dinv, int n, int nbkt, int e) {
    __shared__ unsigned cnt[64][SBS], lofs[64][SBS], cur[64][SBS];
    __shared__ unsigned wsum[64], tbase[64], ttot[64];
    int bk = blockIdx.x;
    int zs = (int)histBase[(size_t)bk * NBLK];
    int ze = (bk + 1 < nbkt) ? (int)histBase[(size_t)(bk + 1) * NBLK] : e;
    int t = threadIdx.x;
    for (int k = t; k < 64 * SBS; k += 256) {
        (&cnt[0][0])[k] = 0;
        (&cur[0][0])[k] = 0;
    }
    if (t < 64) wsum[t] = 0;
    __syncthreads();
    for (int p = zs + t; p < ze; p += 256) {
        unsigned v = pay[p];
        int l = (int)(v >> 26);
        int sb = (int)(((v >> 9) & 0x1ffffu) >> 13);   // src block
        atomicAdd(&cnt[l][sb], 1u);
        atomicAdd(&wsum[l], v & 0x1ffu);
    }
    __syncthreads();
    if (t < 64) {
        unsigned s = 0;
        #pragma unroll
        for (int j = 0; j < SBS; ++j) s += cnt[t][j];
        ttot[t] = s;
    }
    __syncthreads();
    if (t == 0) {
        unsigned run = 0;
        for (int l = 0; l < 64; ++l) { tbase[l] = run; run += ttot[l]; }
    }
    __syncthreads();
    if (t < 64) {
        unsigned run = tbase[t];
        #pragma unroll
        for (int j = 0; j < SBS; ++j) { lofs[t][j] = run; run += cnt[t][j]; }
    }
    __syncthreads();
    for (int p = zs + t; p < ze; p += 256) {       // zone is L2-hot (8KB)
        unsigned v = pay[p];
        int l = (int)(v >> 26);
        unsigned lo = v & 0x03ffffffu;             // src<<9 | q9
        int sb = (int)((lo >> 9) >> 13);
        unsigned rk = atomicAdd(&cur[l][sb], 1u);
        csr[zs + lofs[l][sb] + rk] = lo;
    }
    if (t < 64) {
        int node = bk * 64 + t;
        if (node < n) {
            offs[node] = zs + (int)tbase[t];
            float dg = 1.0f + (float)wsum[t] * (1.0f / Q9);  // self-loop
            dinv[node] = rsqrtf(dg);
        }
    }
}

// ---- csr2_fill: csr2 = src<<15 | q15(dinv[src]*ew)  (order-preserving) ----
__global__ __launch_bounds__(256) void csr2_fill(const unsigned* __restrict__ csr,
                                                 const float* __restrict__ dinv,
                                                 unsigned* __restrict__ csr2, int e) {
    int i = blockIdx.x * 256 + threadIdx.x;
    if (i < e) {
        unsigned v = csr[i];
        unsigned src = v >> 9;
        float a = dinv[src] * ((float)(v & 0x1ffu) * (1.0f / Q9));
        csr2[i] = (src << 15) | (unsigned)(a * QSCALE + 0.5f);
    }
}

// ---- aggregate: one wave per node, lane owns 2 channels (bf16x2 u32) ------
// Single pass; edge lists are src-sorted (p3) so gathers sweep h coherently.
// csr2 NT-loaded; out NT-stored. XCD-chunked swizzle.
__global__ __launch_bounds__(256) void aggregate_kernel(
    const unsigned* __restrict__ h, const unsigned* __restrict__ csr2,
    const int* __restrict__ offs, const float* __restrict__ dinv,
    const float* __restrict__ bias, const float* __restrict__ alpha,
    float* __restrict__ out, int n, int swzq) {
    int bid = blockIdx.x;
    int sb  = swzq ? ((bid & 7) * swzq + (bid >> 3)) : bid;   // bijective: grid%8==0
    int w = sb * 4 + (threadIdx.x >> 6);
    if (w >= n) return;
    int lane = threadIdx.x & 63;

    int beg = __builtin_amdgcn_readfirstlane(offs[w]);
    int end = __builtin_amdgcn_readfirstlane(offs[w + 1]);
    float ax = 0.0f, ay = 0.0f;

    int i = beg;
    int end4 = beg + ((end - beg) & ~3);
    for (; i < end4; i += 4) {
        unsigned v0 = __builtin_nontemporal_load(&csr2[i]);
        unsigned v1 = __builtin_nontemporal_load(&csr2[i + 1]);
        unsigned v2 = __builtin_nontemporal_load(&csr2[i + 2]);
        unsigned v3 = __builtin_nontemporal_load(&csr2[i + 3]);
        unsigned u0 = h[(size_t)(v0 >> 15) * 64 + lane];
        unsigned u1 = h[(size_t)(v1 >> 15) * 64 + lane];
        unsigned u2 = h[(size_t)(v2 >> 15) * 64 + lane];
        unsigned u3 = h[(size_t)(v3 >> 15) * 64 + lane];
        float a0 = (float)(v0 & 0x7fffu) * (1.0f / QSCALE);
        float a1 = (float)(v1 & 0x7fffu) * (1.0f / QSCALE);
        float a2 = (float)(v2 & 0x7fffu) * (1.0f / QSCALE);
        float a3 = (float)(v3 & 0x7fffu) * (1.0f / QSCALE);
        float2 h0 = bf16unpack2(u0), h1 = bf16unpack2(u1);
        float2 h2 = bf16unpack2(u2), h3 = bf16unpack2(u3);
        ax += a0 * h0.x; ay += a0 * h0.y;
        ax += a1 * h1.x; ay += a1 * h1.y;
        ax += a2 * h2.x; ay += a2 * h2.y;
        ax += a3 * h3.x; ay += a3 * h3.y;
    }
    for (; i < end; ++i) {
        unsigned v = __builtin_nontemporal_load(&csr2[i]);
        unsigned u = h[(size_t)(v >> 15) * 64 + lane];
        float a = (float)(v & 0x7fffu) * (1.0f / QSCALE);
        float2 hv = bf16unpack2(u);
        ax += a * hv.x; ay += a * hv.y;
    }

    float dc = dinv[w];
    float2 hc = bf16unpack2(h[(size_t)w * 64 + lane]);  // self: dinv^2 * h[c]
    ax += dc * hc.x; ay += dc * hc.y;

    float2 bv = ((const float2*)bias)[lane];
    float2 av = ((const float2*)alpha)[lane];
    float ox = ax * dc + bv.x;
    float oy = ay * dc + bv.y;
    ox = ox > 0.0f ? ox : av.x * ox;
    oy = oy > 0.0f ? oy : av.y * oy;
    vfloat2 ov; ov.x = ox; ov.y = oy;
    __builtin_nontemporal_store(ov,
        (vfloat2*)&((float2*)out)[(size_t)w * 64 + lane]);
}

extern "C" void kernel_launch(void* const* d_in, const int* in_sizes, int n_in,
                              void* d_out, int out_size, void* d_ws, size_t ws_size,
                              hipStream_t stream) {
    const float* x     = (const float*)d_in[0];
    const int*   ei    = (const int*)d_in[1];
    const float* ew    = (const float*)d_in[2];
    const float* W     = (const float*)d_in[3];
    const float* bias  = (const float*)d_in[4];
    const float* alpha = (const float*)d_in[5];
    float* out = (float*)d_out;

    const int n = in_sizes[0] / 128;   // 100000
    const int e = in_sizes[1] / 2;     // 3200000
    const int* row = ei;               // edge_index[0] = source (gather)
    const int* col = ei + e;           // edge_index[1] = target (scatter)

    const int nbkt = (n + 63) >> 6;            // 1563 buckets of 64 nodes
    const int m    = nbkt * NBLK;              // 800256 (bucket,block) counts
    const int epb  = (e + NBLK - 1) / NBLK;    // 6250 edges per p2 block
    const int nb2  = (m + 1023) / 1024;        // 782 scan blocks (<=1024)

    // workspace carve-out (256B aligned): ~68 MB total
    char* ws = (char*)d_ws;
    size_t off = 0;
    auto alloc = [&](size_t bytes) -> char* {
        char* p = ws + off;
        off = (off + bytes + 255) & ~(size_t)255;
        return p;
    };
    unsigned* hist = (unsigned*)alloc((size_t)m * 4);
    unsigned* part = (unsigned*)alloc((size_t)1024 * 4);
    int*      offs = (int*)     alloc((size_t)(n + 1) * 4);
    float*    dinv = (float*)   alloc((size_t)n * 4);
    unsigned* pay  = (unsigned*)alloc((size_t)e * 4);
    unsigned* csr  = (unsigned*)alloc((size_t)e * 4);
    unsigned* csr2 = (unsigned*)alloc((size_t)e * 4);
    unsigned* h    = (unsigned*)alloc((size_t)n * 128 * 2);
    (void)ws_size; (void)n_in; (void)out_size;

    int gg = (n + 63) / 64;  // 1563 gemm-role blocks

    p1_hist<<<NBLK, 256, 0, stream>>>(col, hist, e, nbkt, epb);
    scan_partial2<<<nb2, 1024, 0, stream>>>(hist, part, m);
    scan_base2<<<1, 1024, 0, stream>>>(part, nb2, offs, n, e);
    scan_write2<<<nb2, 1024, 0, stream>>>(hist, part, m);
    fused_p2_gemm<<<NBLK + gg, 256, 0, stream>>>(col, row, ew, hist, pay,
                                                 e, nbkt, epb, x, W, h, n);
    p3_build<<<nbkt, 256, 0, stream>>>(pay, hist, csr, offs, dinv, n, nbkt, e);
    csr2_fill<<<(e + 255) / 256, 256, 0, stream>>>(csr, dinv, csr2, e);

    int ga = (n + 3) / 4;    // 4 nodes (waves) per 256-thread block
    int swzq = (ga % 8 == 0) ? ga / 8 : 0;
    aggregate_kernel<<<ga, 256, 0, stream>>>(h, csr2, offs, dinv,
                                             bias, alpha, out, n, swzq);
}